// Round 10
// baseline (133.407 us; speedup 1.0000x reference)
//
#include <hip/hip_runtime.h>
#include <math.h>

#define D_MODEL 1024
#define NHEAD   16
#define DKK     64
#define BATCH   2
#define SEQ     2048
#define MROWS   (BATCH*SEQ)   // 4096
#define KVCH    1024          // KV chunk (flash-decoding split x2)

typedef __attribute__((ext_vector_type(8)))  short bf16x8;   // 8 bf16 (4 VGPRs)
typedef __attribute__((ext_vector_type(4)))  short bf16x4;   // 8 B
typedef __attribute__((ext_vector_type(4)))  float f32x4;    // 16x16 accumulator
typedef __attribute__((ext_vector_type(16))) float f32x16;   // 32x32 accumulator

#define MFMA(a,b,c)   __builtin_amdgcn_mfma_f32_16x16x32_bf16((a),(b),(c),0,0,0)
#define MFMA32(a,b,c) __builtin_amdgcn_mfma_f32_32x32x16_bf16((a),(b),(c),0,0,0)

#define QSCALE 0.18033688f   // 0.125 * log2(e): folded into Q so p = exp2(S)

#define SBAR() { __builtin_amdgcn_sched_barrier(0); \
                 __builtin_amdgcn_s_barrier();      \
                 __builtin_amdgcn_sched_barrier(0); }

__device__ __forceinline__ short f2b(float f) {
    unsigned u = __float_as_uint(f);
    unsigned r = (u + 0x7FFFu + ((u >> 16) & 1u)) >> 16;   // RNE
    return (short)r;
}
__device__ __forceinline__ float b2f(short s) {
    return __uint_as_float(((unsigned)(unsigned short)s) << 16);
}

__device__ __forceinline__ float fexp2(float x) {
    float r; asm("v_exp_f32 %0, %1" : "=v"(r) : "v"(x)); return r;
}

__device__ __forceinline__ void gld_lds16(const void* g, void* l) {
    __builtin_amdgcn_global_load_lds(
        (const __attribute__((address_space(1))) void*)g,
        (__attribute__((address_space(3))) void*)l, 16, 0, 0);
}

// ---------------------------------------------------------------------------
// Weight prep: W[1024][1024] f32 -> WT bf16 [N][K].  z=0..2 -> wt3, z=3 -> wot
// ---------------------------------------------------------------------------
__global__ __launch_bounds__(256)
void prep_weights(const float* __restrict__ Wq, const float* __restrict__ Wk,
                  const float* __restrict__ Wv, const float* __restrict__ Wo,
                  short* __restrict__ wt3, short* __restrict__ wot)
{
    const int z = blockIdx.z;
    const float* W = z==0 ? Wq : z==1 ? Wk : z==2 ? Wv : Wo;
    short* dst = (z < 3) ? (wt3 + (size_t)z*1024*1024) : wot;
    __shared__ float tile[32][33];
    const int tx = threadIdx.x & 31, ty = threadIdx.x >> 5;
    const int c0 = blockIdx.x*32, r0 = blockIdx.y*32;
    #pragma unroll
    for (int i = 0; i < 4; i++)
        tile[ty + i*8][tx] = W[(size_t)(r0 + ty + i*8)*1024 + c0 + tx];
    __syncthreads();
    #pragma unroll
    for (int i = 0; i < 4; i++)
        dst[(size_t)(c0 + ty + i*8)*1024 + r0 + tx] = f2b(tile[tx][ty + i*8]);
}

__global__ __launch_bounds__(256)
void convert_x(const float* __restrict__ x, short* __restrict__ xb)
{
    const int i = (blockIdx.x*256 + threadIdx.x) * 8;
    float4 a = *(const float4*)(x + i);
    float4 c = *(const float4*)(x + i + 4);
    bf16x8 v;
    v[0]=f2b(a.x); v[1]=f2b(a.y); v[2]=f2b(a.z); v[3]=f2b(a.w);
    v[4]=f2b(c.x); v[5]=f2b(c.y); v[6]=f2b(c.z); v[7]=f2b(c.w);
    *(bf16x8*)(xb + i) = v;
}

// ---------------------------------------------------------------------------
// Fused QKV GEMM, 256x192-tile 8-phase schedule (T2+T3+T4+T5).  (round-9 form)
// ---------------------------------------------------------------------------
__global__ __launch_bounds__(512, 2)
void gemm_qkv(const short* __restrict__ A, const short* __restrict__ Bt,
              const float* __restrict__ bq, const float* __restrict__ bk,
              const float* __restrict__ bv,
              short* __restrict__ qb, short* __restrict__ kb, short* __restrict__ vtb)
{
    __shared__ short Ab[2*16384];   // [buf][256 rows][64 k]   64 KB
    __shared__ short Bb[2*12288];   // [buf][192 rows][64 k]   48 KB

    const int t = threadIdx.x;              // 0..511
    const int w = t >> 6, lane = t & 63;
    const int r = lane & 15, g4 = lane >> 4;
    const int wm = w >> 2, wn = w & 3;      // wave grid 2(M) x 4(N)

    // XCD rect swizzle: 256 blocks = 8 XCD x 32; each XCD a 4m x 8n rect.
    const int bid = blockIdx.x;
    const int xcd = bid & 7, idx = bid >> 3;          // idx 0..31
    const int mi  = (xcd >> 1) * 4 + (idx & 3);       // 0..15
    const int ni  = (xcd & 1) * 8 + (idx >> 2);       // 0..15
    const int m0 = mi * 256, n0 = ni * 192;

    const int srow = t >> 3;                          // 0..63
    const int scol = ((t & 7) ^ (srow & 7)) * 8;

    f32x4 acc[8][3] = {};
    bf16x8 bfr[2][3];   // B-frags per k-slice, live across the two m-halves

#define QKV_STAGE(P, KT)                                                      \
    { const int kk = (KT) * 64 + scol;                                        \
      _Pragma("unroll")                                                       \
      for (int a = 0; a < 4; a++)                                             \
          gld_lds16(A + (size_t)(m0 + a*64 + srow)*1024 + kk,                 \
                    Ab + (P)*16384 + a*4096 + t*8);                           \
      _Pragma("unroll")                                                       \
      for (int p2 = 0; p2 < 3; p2++)                                          \
          gld_lds16(Bt + (size_t)(n0 + p2*64 + srow)*1024 + kk,               \
                    Bb + (P)*12288 + p2*4096 + t*8); }

#define QKV_PHASE(P, MH, KS, LOADB)                                           \
    { const short* Abase = Ab + (P)*16384 + wm*8192;                          \
      bf16x8 af[4];                                                           \
      _Pragma("unroll")                                                       \
      for (int i = 0; i < 4; i++)                                             \
          af[i] = *(const bf16x8*)&Abase[((MH)*64 + i*16 + r)*64 +            \
                                         (((KS)*4 + g4) ^ (r&7))*8];          \
      if (LOADB) {                                                            \
          const short* Bbase = Bb + (P)*12288;                                \
          _Pragma("unroll")                                                   \
          for (int j = 0; j < 3; j++)                                         \
              bfr[KS][j] = *(const bf16x8*)&Bbase[(wn*48 + j*16 + r)*64 +     \
                                                  (((KS)*4 + g4) ^ (r&7))*8]; \
      }                                                                       \
      SBAR();                                                                 \
      __builtin_amdgcn_s_setprio(1);                                          \
      _Pragma("unroll")                                                       \
      for (int i = 0; i < 4; i++)                                             \
          _Pragma("unroll")                                                   \
          for (int j = 0; j < 3; j++)                                         \
              acc[(MH)*4+i][j] = MFMA(af[i], bfr[KS][j], acc[(MH)*4+i][j]);   \
      __builtin_amdgcn_s_setprio(0);                                          \
      SBAR(); }

    QKV_STAGE(0, 0)
    QKV_STAGE(1, 1)
    asm volatile("s_waitcnt vmcnt(7)" ::: "memory");
    __builtin_amdgcn_s_barrier();
    __builtin_amdgcn_sched_barrier(0);

    int p = 0;
    #pragma unroll 1
    for (int kt = 0; kt < 16; kt++) {
        QKV_PHASE(p, 0, 0, 1)
        QKV_PHASE(p, 1, 0, 0)
        QKV_PHASE(p, 0, 1, 1)
        QKV_PHASE(p, 1, 1, 0)
        if (kt < 14) {
            QKV_STAGE(p, kt + 2)
            asm volatile("s_waitcnt vmcnt(7)" ::: "memory");  // kt+1 landed
        } else {
            asm volatile("s_waitcnt vmcnt(0)" ::: "memory");  // tail drain
        }
        __builtin_amdgcn_s_barrier();
        __builtin_amdgcn_sched_barrier(0);
        p ^= 1;
    }
#undef QKV_STAGE
#undef QKV_PHASE

    #pragma unroll
    for (int n = 0; n < 3; n++) {
        const int colbase = n0 + wn*48 + n*16;
        const int proj    = colbase >> 10;
        const int within  = colbase & 1023;
        const int h       = within >> 6;
        const int d       = (within & 63) + r;
        const float* bias = (proj == 0) ? bq : (proj == 1) ? bk : bv;
        const float bval  = bias[within + r];
        #pragma unroll
        for (int m = 0; m < 8; m++) {
            const int growb = m0 + wm*128 + m*16 + g4*4;
            const int bidx  = growb >> 11;
            const int s     = growb & 2047;
            if (proj == 0) {
                #pragma unroll
                for (int i = 0; i < 4; i++)
                    qb[((size_t)(bidx*NHEAD + h)*SEQ + s + i)*DKK + d] =
                        f2b((acc[m][n][i] + bval) * QSCALE);
            } else if (proj == 1) {
                #pragma unroll
                for (int i = 0; i < 4; i++)
                    kb[((size_t)(bidx*NHEAD + h)*SEQ + s + i)*DKK + d] =
                        f2b(acc[m][n][i] + bval);
            } else {
                bf16x4 pk;
                #pragma unroll
                for (int i = 0; i < 4; i++) pk[i] = f2b(acc[m][n][i] + bval);
                *(bf16x4*)(vtb + ((size_t)(bidx*NHEAD + h)*DKK + d)*SEQ + s) = pk;
            }
        }
    }
}

// ---------------------------------------------------------------------------
// Wo GEMM + bias + residual -> h fp32.  128x64 tile, double-buffered + swizzle.
// ---------------------------------------------------------------------------
__global__ __launch_bounds__(256)
void gemm_out(const short* __restrict__ A, const short* __restrict__ Bt,
              const float* __restrict__ bo, const float* __restrict__ resid,
              float* __restrict__ hb)
{
    __shared__ short As[2*128*32];   // 16 KB
    __shared__ short Bs[2*64*32];    // 8 KB
    const int t = threadIdx.x;
    const int w = t >> 6, lane = t & 63;
    const int r = lane & 15, g4 = lane >> 4;
    const int wr = w >> 1, wc = w & 1;

    const int bid = blockIdx.x;
    const int xcd = bid & 7, idx = bid >> 3;          // idx 0..63
    const int mi  = (xcd >> 1) * 8 + (idx & 7);       // 0..31
    const int ni  = (xcd & 1) * 8 + (idx >> 3);       // 0..15
    const int m0 = mi * 128, n0 = ni * 64;

    const int srow = lane >> 2, su = lane & 3;

    f32x4 acc[4][2] = {};

#define OUT_STAGE(BUF, K0)                                                     \
    { const int kk = (K0) & 1023;                                              \
      _Pragma("unroll")                                                        \
      for (int c = 0; c < 2; c++) {                                            \
          const int row = w*32 + c*16 + srow;                                  \
          gld_lds16(A + (size_t)(m0+row)*1024 + kk + 8*(su ^ ((row>>1)&3)),    \
                    As + (BUF)*4096 + w*1024 + c*512);                         \
      }                                                                        \
      { const int row = w*16 + srow;                                           \
        gld_lds16(Bt + (size_t)(n0+row)*1024 + kk + 8*(su ^ ((row>>1)&3)),     \
                  Bs + (BUF)*2048 + w*512); } }

    OUT_STAGE(0, 0)
    __syncthreads();

    int cur = 0;
    #pragma unroll 1
    for (int k0 = 0; k0 < 1024; k0 += 32) {
        OUT_STAGE(cur^1, k0 + 32)
        const short* Abase = As + cur*4096;
        const short* Bbase = Bs + cur*2048;
        bf16x8 af[4], bfr[2];
        #pragma unroll
        for (int m = 0; m < 4; m++) {
            const int row = wr*64 + m*16 + r;
            af[m] = *(const bf16x8*)&Abase[row*32 + (g4 ^ ((row>>1)&3))*8];
        }
        #pragma unroll
        for (int n = 0; n < 2; n++) {
            const int row = wc*32 + n*16 + r;
            bfr[n] = *(const bf16x8*)&Bbase[row*32 + (g4 ^ ((row>>1)&3))*8];
        }
        __builtin_amdgcn_s_setprio(1);
        #pragma unroll
        for (int m = 0; m < 4; m++)
            #pragma unroll
            for (int n = 0; n < 2; n++)
                acc[m][n] = MFMA(af[m], bfr[n], acc[m][n]);
        __builtin_amdgcn_s_setprio(0);
        __syncthreads();
        cur ^= 1;
    }
#undef OUT_STAGE

    #pragma unroll
    for (int n = 0; n < 2; n++) {
        const int col = n0 + wc*32 + n*16 + r;
        const float bval = bo[col];
        #pragma unroll
        for (int m = 0; m < 4; m++) {
            #pragma unroll
            for (int i = 0; i < 4; i++) {
                const int grow = m0 + wr*64 + m*16 + g4*4 + i;
                const size_t ofs = (size_t)grow*1024 + col;
                hb[ofs] = acc[m][n][i] + bval + resid[ofs];
            }
        }
    }
}

// ---------------------------------------------------------------------------
// Flash-decoding swapped-QK 32x32 MFMA attention, LDS-staged K/V.
// Grid 1024 = 32 bh x 16 qt x 2 KV-chunks (KVCH=1024).  Block = 4 waves x
// 32 q-rows.  No max tracking; Q pre-scaled.  l computed via ones-MFMA
// (lacc = P @ 1) -- removes the serial 15-add tree + 16 adds per tile.
// Writes un-normalized partial O (bf16) + partial l; combine sums.
// ---------------------------------------------------------------------------
__global__ __launch_bounds__(256, 3)
void attn_fd(const short* __restrict__ Q, const short* __restrict__ K,
             const short* __restrict__ VT, short* __restrict__ op0,
             short* __restrict__ op1, float* __restrict__ lpart)
{
    __shared__ short Ks[2*64*64];   // 16 KB
    __shared__ short Vs[2*64*64];   // 16 KB

    const int t = threadIdx.x;
    const int w = t >> 6, lane = t & 63;
    const int l31 = lane & 31, hi = lane >> 5;
    const int srow8 = lane >> 3, su = lane & 7;
    const int lane8 = lane * 8;
    const int swz8  = (su ^ srow8) * 8;

    // XCD swizzle: 1024 blocks; each XCD's 128 logical blocks share 4 bh
    // pairs (2 MB K/V < 4 MB XCD-L2).
    const int bid     = blockIdx.x;
    const int logical = (bid & 7) * 128 + (bid >> 3);
    const int bh_lin  = logical >> 5;              // 0..31
    const int rem     = logical & 31;
    const int qt      = rem >> 1;                  // 0..15
    const int chunk   = rem & 1;
    const int b = bh_lin >> 4, h = bh_lin & 15;
    const int q0 = qt * 128 + w * 32;
    const int cb = chunk * KVCH;

    const size_t bh = (size_t)b * NHEAD + h;
    const short* Qp = Q  + bh * SEQ * DKK;
    const short* Kp = K  + bh * SEQ * DKK;
    const short* Vp = VT + bh * DKK * SEQ;

    const short* kstage = Kp + (size_t)(w*8 + srow8) * DKK + swz8;
    const short* vstage = Vp + (size_t)(w*8 + srow8) * SEQ + swz8;

    bf16x8 qf[4];
    #pragma unroll
    for (int d0 = 0; d0 < 4; d0++)
        qf[d0] = *(const bf16x8*)(Qp + (size_t)(q0 + l31)*DKK + d0*16 + hi*8);

    int koff[8], voff[8];
    #pragma unroll
    for (int i = 0; i < 8; i++) {
        const int rrk = (i>>2)*32 + l31;
        koff[i] = rrk*64 + ((((i&3)*2 + hi) ^ (l31 & 7)) * 8);
        const int dv  = (i&1)*32 + l31;
        voff[i] = dv*64 + ((((i>>1)*2 + hi) ^ (l31 & 7)) * 8);
    }

    const short oneb = 0x3F80;   // bf16 1.0
    bf16x8 onesv = {oneb,oneb,oneb,oneb,oneb,oneb,oneb,oneb};

    f32x16 o0 = {}, o1 = {}, lacc = {};

#define ATT_STAGE(KDST, VDST, JABS)                                            \
    { const size_t jj = (size_t)(JABS);                                        \
      const short* ksrc = kstage + jj*DKK;                                     \
      gld_lds16(ksrc,           (KDST) + w*512 + lane8);                       \
      gld_lds16(ksrc + 32*DKK,  (KDST) + 2048 + w*512 + lane8);                \
      const short* vsrc = vstage + jj;                                         \
      gld_lds16(vsrc,           (VDST) + w*512 + lane8);                       \
      gld_lds16(vsrc + 32*SEQ,  (VDST) + 2048 + w*512 + lane8); }

    // prologue: stage tile 0 of this chunk into buffer 0
    ATT_STAGE(Ks, Vs, cb)
    __syncthreads();

    int cur = 0;
    #pragma unroll 1
    for (int j0 = 0; j0 < KVCH; j0 += 64) {
        ATT_STAGE(Ks + (cur^1)*4096, Vs + (cur^1)*4096,
                  cb + ((j0 + 64) & (KVCH - 1)))

        const short* Kb = Ks + cur*4096;
        const short* Vb = Vs + cur*4096;

        bf16x8 kf[8];
        #pragma unroll
        for (int i = 0; i < 8; i++) kf[i] = *(const bf16x8*)&Kb[koff[i]];
        f32x16 s0 = {}, s1 = {};
        __builtin_amdgcn_s_setprio(1);
        #pragma unroll
        for (int d0 = 0; d0 < 4; d0++) s0 = MFMA32(kf[d0],   qf[d0], s0);
        #pragma unroll
        for (int d0 = 0; d0 < 4; d0++) s1 = MFMA32(kf[4+d0], qf[d0], s1);
        __builtin_amdgcn_s_setprio(0);

        #pragma unroll
        for (int r = 0; r < 16; r++) s0[r] = fexp2(s0[r]);
        #pragma unroll
        for (int r = 0; r < 16; r++) s1[r] = fexp2(s1[r]);

        bf16x8 vf[8];
        #pragma unroll
        for (int i = 0; i < 8; i++) vf[i] = *(const bf16x8*)&Vb[voff[i]];

        // T12: cvt_pk + permlane32_swap -> PV (+ l via ones-MFMA)
        #pragma unroll
        for (int ks = 0; ks < 4; ks++) {
            const int g = (ks & 1) * 8;
            float e0,e1,e2,e3,e4,e5,e6,e7;
            if (ks < 2) { e0=s0[g+0];e1=s0[g+1];e2=s0[g+2];e3=s0[g+3];
                          e4=s0[g+4];e5=s0[g+5];e6=s0[g+6];e7=s0[g+7]; }
            else        { e0=s1[g+0];e1=s1[g+1];e2=s1[g+2];e3=s1[g+3];
                          e4=s1[g+4];e5=s1[g+5];e6=s1[g+6];e7=s1[g+7]; }
            unsigned u0,u1,u2,u3;
            asm("v_cvt_pk_bf16_f32 %0, %1, %2" : "=v"(u0) : "v"(e0), "v"(e1));
            asm("v_cvt_pk_bf16_f32 %0, %1, %2" : "=v"(u1) : "v"(e2), "v"(e3));
            asm("v_cvt_pk_bf16_f32 %0, %1, %2" : "=v"(u2) : "v"(e4), "v"(e5));
            asm("v_cvt_pk_bf16_f32 %0, %1, %2" : "=v"(u3) : "v"(e6), "v"(e7));
            auto rA = __builtin_amdgcn_permlane32_swap(u0, u2, false, false);
            auto rB = __builtin_amdgcn_permlane32_swap(u1, u3, false, false);
            union { unsigned u[4]; bf16x8 v; } pa;
            pa.u[0] = rA[0]; pa.u[1] = rB[0]; pa.u[2] = rA[1]; pa.u[3] = rB[1];
            __builtin_amdgcn_s_setprio(1);
            o0   = MFMA32(pa.v, vf[ks*2+0], o0);
            o1   = MFMA32(pa.v, vf[ks*2+1], o1);
            lacc = MFMA32(pa.v, onesv,      lacc);
            __builtin_amdgcn_s_setprio(0);
        }

        __syncthreads();
        cur ^= 1;
    }

    // epilogue: un-normalized partial O (bf16) + partial l (lacc[0] = l[q=l31])
    short* opc = chunk ? op1 : op0;
    #pragma unroll
    for (int r = 0; r < 16; r++) {
        const int crow = (r&3) + 8*(r>>2) + 4*hi;
        const size_t base = ((size_t)b*SEQ + q0 + crow)*D_MODEL + h*DKK + l31;
        opc[base]      = f2b(o0[r]);
        opc[base + 32] = f2b(o1[r]);
    }
    if (hi == 0)
        lpart[((size_t)chunk*MROWS + (size_t)b*SEQ + q0 + l31)*NHEAD + h] = lacc[0];
#undef ATT_STAGE
}

// ---------------------------------------------------------------------------
// Combine: ctx[row][d] = (O0 + O1) / (l0 + l1), bf16 out. One block per row.
// ---------------------------------------------------------------------------
__global__ __launch_bounds__(256)
void attn_combine(const short* __restrict__ op0, const short* __restrict__ op1,
                  const float* __restrict__ lpart, short* __restrict__ ctx)
{
    const int row = blockIdx.x;            // 0..4095 = b*SEQ+s
    const int t = threadIdx.x;
    const int d4 = t * 4;
    const int h = d4 >> 6;
    const float l0 = lpart[(size_t)row*NHEAD + h];
    const float l1 = lpart[((size_t)MROWS + row)*NHEAD + h];
    const float inv = 1.f / (l0 + l1);
    const size_t ofs = (size_t)row*D_MODEL + d4;
    bf16x4 a = *(const bf16x4*)(op0 + ofs);
    bf16x4 c = *(const bf16x4*)(op1 + ofs);
    bf16x4 o;
    #pragma unroll
    for (int i = 0; i < 4; i++) o[i] = f2b((b2f(a[i]) + b2f(c[i])) * inv);
    *(bf16x4*)(ctx + ofs) = o;
}

// ---------------------------------------------------------------------------
// Row LayerNorm (fp32 in/out)
// ---------------------------------------------------------------------------
__global__ __launch_bounds__(256)
void ln_kernel(const float* __restrict__ hbuf, const float* __restrict__ gamma,
               const float* __restrict__ beta, float* __restrict__ out)
{
    const int row = blockIdx.x;
    const int t = threadIdx.x;
    const float* hp = hbuf + (size_t)row * D_MODEL;
    float4 v = ((const float4*)hp)[t];
    float sum = v.x + v.y + v.z + v.w;
    float sq  = v.x*v.x + v.y*v.y + v.z*v.z + v.w*v.w;
    #pragma unroll
    for (int o = 1; o <= 32; o <<= 1) {
        sum += __shfl_xor(sum, o);
        sq  += __shfl_xor(sq, o);
    }
    __shared__ float s1[4], s2[4];
    if ((t & 63) == 0) { s1[t >> 6] = sum; s2[t >> 6] = sq; }
    __syncthreads();
    sum = s1[0] + s1[1] + s1[2] + s1[3];
    sq  = s2[0] + s2[1] + s2[2] + s2[3];
    const float mean = sum * (1.0f / D_MODEL);
    const float var  = sq * (1.0f / D_MODEL) - mean * mean;
    const float inv  = rsqrtf(var + 1e-5f);
    float4 g  = ((const float4*)gamma)[t];
    float4 be = ((const float4*)beta)[t];
    float4 rr;
    rr.x = (v.x - mean) * inv * g.x + be.x;
    rr.y = (v.y - mean) * inv * g.y + be.y;
    rr.z = (v.z - mean) * inv * g.z + be.z;
    rr.w = (v.w - mean) * inv * g.w + be.w;
    ((float4*)(out + (size_t)row * D_MODEL))[t] = rr;
}

// ---------------------------------------------------------------------------
// Workspace (MiB): xb[0,8) wt3[8,14) wot[14,16) qb[16,24) kb[24,32)
// vtb[32,40) cxb[40,48) hb[48,64) f32.  Lifetime aliases:
//   op0 [0,8)   over xb   (dead after gemm_qkv)
//   lpart [8,8.5) over wt3 (dead after gemm_qkv)
//   op1 [48,56) over hb   (hb written by gemm_out AFTER combine reads op1)
// ---------------------------------------------------------------------------
extern "C" void kernel_launch(void* const* d_in, const int* in_sizes, int n_in,
                              void* d_out, int out_size, void* d_ws, size_t ws_size,
                              hipStream_t stream)
{
    const float* x  = (const float*)d_in[0];
    const float* Wq = (const float*)d_in[1];
    const float* bq = (const float*)d_in[2];
    const float* Wk = (const float*)d_in[3];
    const float* bk = (const float*)d_in[4];
    const float* Wv = (const float*)d_in[5];
    const float* bv = (const float*)d_in[6];
    const float* Wo = (const float*)d_in[7];
    const float* bo = (const float*)d_in[8];
    const float* g  = (const float*)d_in[9];
    const float* be = (const float*)d_in[10];

    char* base = (char*)d_ws;
    short* xb    = (short*)base;
    short* wt3   = (short*)(base + (8u<<20));
    short* wot   = (short*)(base + (14u<<20));
    short* qb    = (short*)(base + (16u<<20));
    short* kb    = (short*)(base + (24u<<20));
    short* vtb   = (short*)(base + (32u<<20));
    short* cxb   = (short*)(base + (40u<<20));
    float* hb    = (float*)(base + (48u<<20));
    short* op0   = (short*)base;               // alias xb (dead)
    float* lpart = (float*)(base + (8u<<20)); // alias wt3 (dead)
    short* op1   = (short*)(base + (48u<<20)); // alias hb (written later)

    prep_weights<<<dim3(32,32,4), 256, 0, stream>>>(Wq, Wk, Wv, Wo, wt3, wot);
    convert_x   <<<2048, 256, 0, stream>>>(x, xb);
    gemm_qkv    <<<256, 512, 0, stream>>>(xb, wt3, bq, bk, bv, qb, kb, vtb);
    attn_fd     <<<1024, 256, 0, stream>>>(qb, kb, vtb, op0, op1, lpart);
    attn_combine<<<MROWS, 256, 0, stream>>>(op0, op1, lpart, cxb);
    gemm_out    <<<512, 256, 0, stream>>>(cxb, wot, bo, x, hb);
    ln_kernel   <<<MROWS, 256, 0, stream>>>(hb, g, be, (float*)d_out);
}

// Round 11
// 124.664 us; speedup vs baseline: 1.0701x; 1.0701x over previous
//
#include <hip/hip_runtime.h>
#include <math.h>

#define D_MODEL 1024
#define NHEAD   16
#define DKK     64
#define BATCH   2
#define SEQ     2048
#define MROWS   (BATCH*SEQ)   // 4096

typedef __attribute__((ext_vector_type(8)))  short bf16x8;   // 8 bf16 (4 VGPRs)
typedef __attribute__((ext_vector_type(4)))  short bf16x4;   // 8 B
typedef __attribute__((ext_vector_type(4)))  float f32x4;    // 16x16 accumulator
typedef __attribute__((ext_vector_type(16))) float f32x16;   // 32x32 accumulator

#define MFMA(a,b,c)   __builtin_amdgcn_mfma_f32_16x16x32_bf16((a),(b),(c),0,0,0)
#define MFMA32(a,b,c) __builtin_amdgcn_mfma_f32_32x32x16_bf16((a),(b),(c),0,0,0)

#define QSCALE 0.18033688f   // 0.125 * log2(e): folded into Q so p = exp2(S)

#define SBAR() { __builtin_amdgcn_sched_barrier(0); \
                 __builtin_amdgcn_s_barrier();      \
                 __builtin_amdgcn_sched_barrier(0); }

// padded LDS chunk geometry for attn tiles: 8 rows x 64 shorts + 8 pad
#define CH  520              // shorts per 8-row chunk
#define TIL (8*CH)           // 4160 shorts per 64x64 tile

__device__ __forceinline__ short f2b(float f) {
    unsigned u = __float_as_uint(f);
    unsigned r = (u + 0x7FFFu + ((u >> 16) & 1u)) >> 16;   // RNE
    return (short)r;
}

__device__ __forceinline__ float fexp2(float x) {
    float r; asm("v_exp_f32 %0, %1" : "=v"(r) : "v"(x)); return r;
}

__device__ __forceinline__ void gld_lds16(const void* g, void* l) {
    __builtin_amdgcn_global_load_lds(
        (const __attribute__((address_space(1))) void*)g,
        (__attribute__((address_space(3))) void*)l, 16, 0, 0);
}

// ---------------------------------------------------------------------------
// Weight prep: W[1024][1024] f32 -> WT bf16 [N][K].  z=0..2 -> wt3, z=3 -> wot
// ---------------------------------------------------------------------------
__global__ __launch_bounds__(256)
void prep_weights(const float* __restrict__ Wq, const float* __restrict__ Wk,
                  const float* __restrict__ Wv, const float* __restrict__ Wo,
                  short* __restrict__ wt3, short* __restrict__ wot)
{
    const int z = blockIdx.z;
    const float* W = z==0 ? Wq : z==1 ? Wk : z==2 ? Wv : Wo;
    short* dst = (z < 3) ? (wt3 + (size_t)z*1024*1024) : wot;
    __shared__ float tile[32][33];
    const int tx = threadIdx.x & 31, ty = threadIdx.x >> 5;
    const int c0 = blockIdx.x*32, r0 = blockIdx.y*32;
    #pragma unroll
    for (int i = 0; i < 4; i++)
        tile[ty + i*8][tx] = W[(size_t)(r0 + ty + i*8)*1024 + c0 + tx];
    __syncthreads();
    #pragma unroll
    for (int i = 0; i < 4; i++)
        dst[(size_t)(c0 + ty + i*8)*1024 + r0 + tx] = f2b(tile[tx][ty + i*8]);
}

__global__ __launch_bounds__(256)
void convert_x(const float* __restrict__ x, short* __restrict__ xb)
{
    const int i = (blockIdx.x*256 + threadIdx.x) * 8;
    float4 a = *(const float4*)(x + i);
    float4 c = *(const float4*)(x + i + 4);
    bf16x8 v;
    v[0]=f2b(a.x); v[1]=f2b(a.y); v[2]=f2b(a.z); v[3]=f2b(a.w);
    v[4]=f2b(c.x); v[5]=f2b(c.y); v[6]=f2b(c.z); v[7]=f2b(c.w);
    *(bf16x8*)(xb + i) = v;
}

// ---------------------------------------------------------------------------
// Fused QKV GEMM, 256x192-tile 8-phase schedule (T2+T3+T4+T5).  (round-9 form)
// ---------------------------------------------------------------------------
__global__ __launch_bounds__(512, 2)
void gemm_qkv(const short* __restrict__ A, const short* __restrict__ Bt,
              const float* __restrict__ bq, const float* __restrict__ bk,
              const float* __restrict__ bv,
              short* __restrict__ qb, short* __restrict__ kb, short* __restrict__ vtb)
{
    __shared__ short Ab[2*16384];   // [buf][256 rows][64 k]   64 KB
    __shared__ short Bb[2*12288];   // [buf][192 rows][64 k]   48 KB

    const int t = threadIdx.x;              // 0..511
    const int w = t >> 6, lane = t & 63;
    const int r = lane & 15, g4 = lane >> 4;
    const int wm = w >> 2, wn = w & 3;      // wave grid 2(M) x 4(N)

    // XCD rect swizzle: 256 blocks = 8 XCD x 32; each XCD a 4m x 8n rect.
    const int bid = blockIdx.x;
    const int xcd = bid & 7, idx = bid >> 3;          // idx 0..31
    const int mi  = (xcd >> 1) * 4 + (idx & 3);       // 0..15
    const int ni  = (xcd & 1) * 8 + (idx >> 2);       // 0..15
    const int m0 = mi * 256, n0 = ni * 192;

    const int srow = t >> 3;                          // 0..63
    const int scol = ((t & 7) ^ (srow & 7)) * 8;

    f32x4 acc[8][3] = {};
    bf16x8 bfr[2][3];   // B-frags per k-slice, live across the two m-halves

#define QKV_STAGE(P, KT)                                                      \
    { const int kk = (KT) * 64 + scol;                                        \
      _Pragma("unroll")                                                       \
      for (int a = 0; a < 4; a++)                                             \
          gld_lds16(A + (size_t)(m0 + a*64 + srow)*1024 + kk,                 \
                    Ab + (P)*16384 + a*4096 + t*8);                           \
      _Pragma("unroll")                                                       \
      for (int p2 = 0; p2 < 3; p2++)                                          \
          gld_lds16(Bt + (size_t)(n0 + p2*64 + srow)*1024 + kk,               \
                    Bb + (P)*12288 + p2*4096 + t*8); }

#define QKV_PHASE(P, MH, KS, LOADB)                                           \
    { const short* Abase = Ab + (P)*16384 + wm*8192;                          \
      bf16x8 af[4];                                                           \
      _Pragma("unroll")                                                       \
      for (int i = 0; i < 4; i++)                                             \
          af[i] = *(const bf16x8*)&Abase[((MH)*64 + i*16 + r)*64 +            \
                                         (((KS)*4 + g4) ^ (r&7))*8];          \
      if (LOADB) {                                                            \
          const short* Bbase = Bb + (P)*12288;                                \
          _Pragma("unroll")                                                   \
          for (int j = 0; j < 3; j++)                                         \
              bfr[KS][j] = *(const bf16x8*)&Bbase[(wn*48 + j*16 + r)*64 +     \
                                                  (((KS)*4 + g4) ^ (r&7))*8]; \
      }                                                                       \
      SBAR();                                                                 \
      __builtin_amdgcn_s_setprio(1);                                          \
      _Pragma("unroll")                                                       \
      for (int i = 0; i < 4; i++)                                             \
          _Pragma("unroll")                                                   \
          for (int j = 0; j < 3; j++)                                         \
              acc[(MH)*4+i][j] = MFMA(af[i], bfr[KS][j], acc[(MH)*4+i][j]);   \
      __builtin_amdgcn_s_setprio(0);                                          \
      SBAR(); }

    QKV_STAGE(0, 0)
    QKV_STAGE(1, 1)
    asm volatile("s_waitcnt vmcnt(7)" ::: "memory");
    __builtin_amdgcn_s_barrier();
    __builtin_amdgcn_sched_barrier(0);

    int p = 0;
    #pragma unroll 1
    for (int kt = 0; kt < 16; kt++) {
        QKV_PHASE(p, 0, 0, 1)
        QKV_PHASE(p, 1, 0, 0)
        QKV_PHASE(p, 0, 1, 1)
        QKV_PHASE(p, 1, 1, 0)
        if (kt < 14) {
            QKV_STAGE(p, kt + 2)
            asm volatile("s_waitcnt vmcnt(7)" ::: "memory");  // kt+1 landed
        } else {
            asm volatile("s_waitcnt vmcnt(0)" ::: "memory");  // tail drain
        }
        __builtin_amdgcn_s_barrier();
        __builtin_amdgcn_sched_barrier(0);
        p ^= 1;
    }
#undef QKV_STAGE
#undef QKV_PHASE

    #pragma unroll
    for (int n = 0; n < 3; n++) {
        const int colbase = n0 + wn*48 + n*16;
        const int proj    = colbase >> 10;
        const int within  = colbase & 1023;
        const int h       = within >> 6;
        const int d       = (within & 63) + r;
        const float* bias = (proj == 0) ? bq : (proj == 1) ? bk : bv;
        const float bval  = bias[within + r];
        #pragma unroll
        for (int m = 0; m < 8; m++) {
            const int growb = m0 + wm*128 + m*16 + g4*4;
            const int bidx  = growb >> 11;
            const int s     = growb & 2047;
            if (proj == 0) {
                #pragma unroll
                for (int i = 0; i < 4; i++)
                    qb[((size_t)(bidx*NHEAD + h)*SEQ + s + i)*DKK + d] =
                        f2b((acc[m][n][i] + bval) * QSCALE);
            } else if (proj == 1) {
                #pragma unroll
                for (int i = 0; i < 4; i++)
                    kb[((size_t)(bidx*NHEAD + h)*SEQ + s + i)*DKK + d] =
                        f2b(acc[m][n][i] + bval);
            } else {
                bf16x4 pk;
                #pragma unroll
                for (int i = 0; i < 4; i++) pk[i] = f2b(acc[m][n][i] + bval);
                *(bf16x4*)(vtb + ((size_t)(bidx*NHEAD + h)*DKK + d)*SEQ + s) = pk;
            }
        }
    }
}

// ---------------------------------------------------------------------------
// Wo GEMM + bias + residual -> h fp32.  128x64 tile, double-buffered + swizzle.
// ---------------------------------------------------------------------------
__global__ __launch_bounds__(256)
void gemm_out(const short* __restrict__ A, const short* __restrict__ Bt,
              const float* __restrict__ bo, const float* __restrict__ resid,
              float* __restrict__ hb)
{
    __shared__ short As[2*128*32];   // 16 KB
    __shared__ short Bs[2*64*32];    // 8 KB
    const int t = threadIdx.x;
    const int w = t >> 6, lane = t & 63;
    const int r = lane & 15, g4 = lane >> 4;
    const int wr = w >> 1, wc = w & 1;

    const int bid = blockIdx.x;
    const int xcd = bid & 7, idx = bid >> 3;          // idx 0..63
    const int mi  = (xcd >> 1) * 8 + (idx & 7);       // 0..31
    const int ni  = (xcd & 1) * 8 + (idx >> 3);       // 0..15
    const int m0 = mi * 128, n0 = ni * 64;

    const int srow = lane >> 2, su = lane & 3;

    f32x4 acc[4][2] = {};

#define OUT_STAGE(BUF, K0)                                                     \
    { const int kk = (K0) & 1023;                                              \
      _Pragma("unroll")                                                        \
      for (int c = 0; c < 2; c++) {                                            \
          const int row = w*32 + c*16 + srow;                                  \
          gld_lds16(A + (size_t)(m0+row)*1024 + kk + 8*(su ^ ((row>>1)&3)),    \
                    As + (BUF)*4096 + w*1024 + c*512);                         \
      }                                                                        \
      { const int row = w*16 + srow;                                           \
        gld_lds16(Bt + (size_t)(n0+row)*1024 + kk + 8*(su ^ ((row>>1)&3)),     \
                  Bs + (BUF)*2048 + w*512); } }

    OUT_STAGE(0, 0)
    __syncthreads();

    int cur = 0;
    #pragma unroll 1
    for (int k0 = 0; k0 < 1024; k0 += 32) {
        OUT_STAGE(cur^1, k0 + 32)
        const short* Abase = As + cur*4096;
        const short* Bbase = Bs + cur*2048;
        bf16x8 af[4], bfr[2];
        #pragma unroll
        for (int m = 0; m < 4; m++) {
            const int row = wr*64 + m*16 + r;
            af[m] = *(const bf16x8*)&Abase[row*32 + (g4 ^ ((row>>1)&3))*8];
        }
        #pragma unroll
        for (int n = 0; n < 2; n++) {
            const int row = wc*32 + n*16 + r;
            bfr[n] = *(const bf16x8*)&Bbase[row*32 + (g4 ^ ((row>>1)&3))*8];
        }
        __builtin_amdgcn_s_setprio(1);
        #pragma unroll
        for (int m = 0; m < 4; m++)
            #pragma unroll
            for (int n = 0; n < 2; n++)
                acc[m][n] = MFMA(af[m], bfr[n], acc[m][n]);
        __builtin_amdgcn_s_setprio(0);
        __syncthreads();
        cur ^= 1;
    }
#undef OUT_STAGE

    #pragma unroll
    for (int n = 0; n < 2; n++) {
        const int col = n0 + wc*32 + n*16 + r;
        const float bval = bo[col];
        #pragma unroll
        for (int m = 0; m < 4; m++) {
            #pragma unroll
            for (int i = 0; i < 4; i++) {
                const int grow = m0 + wr*64 + m*16 + g4*4 + i;
                const size_t ofs = (size_t)grow*1024 + col;
                hb[ofs] = acc[m][n][i] + bval + resid[ofs];
            }
        }
    }
}

// ---------------------------------------------------------------------------
// Swapped-QK 32x32 MFMA flash attention, LDS-staged K/V (round-9 structure)
// + round-11 PADDED-CHUNK layout: each 8-row chunk of the 64x64 tile is 520
// shorts (16-B pad), shifting the bank origin by 4 banks per chunk -- kills
// the 4-way ds_read_b128 conflicts (rows r, r+8, r+16, r+24 shared a bank
// quad in the linear layout).  Staging stays gld_lds-legal: each wave's
// 1024 B write is contiguous within its own chunk.
// ---------------------------------------------------------------------------
__global__ __launch_bounds__(256, 3)
void attn_mfma(const short* __restrict__ Q, const short* __restrict__ K,
               const short* __restrict__ VT, short* __restrict__ ctx)
{
    __shared__ short Ks[2*TIL];   // 16.25 KB
    __shared__ short Vs[2*TIL];   // 16.25 KB

    const int t = threadIdx.x;
    const int w = t >> 6, lane = t & 63;
    const int l31 = lane & 31, hi = lane >> 5;
    const int srow8 = lane >> 3, su = lane & 7;
    const int lane8 = lane * 8;            // element offset within chunk
    const int swz8  = (su ^ srow8) * 8;    // inverse-swizzle on global source

    // T1: XCD-aware swizzle (512 blocks; XCD c owns bh pairs 4c..4c+3).
    const int bid     = blockIdx.x;
    const int logical = (bid & 7) * 64 + (bid >> 3);
    const int bh_lin  = logical >> 4;
    const int qt      = logical & 15;
    const int b = bh_lin >> 4, h = bh_lin & 15;
    const int q0 = qt * 128 + w * 32;

    const size_t bh = (size_t)b * NHEAD + h;
    const short* Qp = Q  + bh * SEQ * DKK;
    const short* Kp = K  + bh * SEQ * DKK;
    const short* Vp = VT + bh * DKK * SEQ;

    // per-thread staging source bases (row = w*8 + srow8, +32 for pass 2)
    const short* kstage = Kp + (size_t)(w*8 + srow8) * DKK + swz8;
    const short* vstage = Vp + (size_t)(w*8 + srow8) * SEQ + swz8;

    // Q B-frags: lane holds Q[q0+l31][d0*16 + hi*8 + j]  (pre-scaled)
    bf16x8 qf[4];
    #pragma unroll
    for (int d0 = 0; d0 < 4; d0++)
        qf[d0] = *(const bf16x8*)(Qp + (size_t)(q0 + l31)*DKK + d0*16 + hi*8);

    // LDS read offsets (tile-invariant; swizzled slot + padded chunk)
    int koff[8], voff[8];
    #pragma unroll
    for (int i = 0; i < 8; i++) {
        const int kchunk = (i>>2)*4 + (l31>>3);
        koff[i] = kchunk*CH + (l31&7)*64 + ((((i&3)*2 + hi) ^ (l31&7)) * 8);
        const int vchunk = (i&1)*4 + (l31>>3);
        voff[i] = vchunk*CH + (l31&7)*64 + ((((i>>1)*2 + hi) ^ (l31&7)) * 8);
    }

    f32x16 o0 = {}, o1 = {};
    float lrow = 0.f;

#define ATT_STAGE(KDST, VDST, J)                                               \
    { const size_t jj = (size_t)((J) & (SEQ-1));                               \
      const short* ksrc = kstage + jj*DKK;                                     \
      gld_lds16(ksrc,           (KDST) + w*CH + lane8);                        \
      gld_lds16(ksrc + 32*DKK,  (KDST) + (4+w)*CH + lane8);                    \
      const short* vsrc = vstage + jj;                                         \
      gld_lds16(vsrc,           (VDST) + w*CH + lane8);                        \
      gld_lds16(vsrc + 32*SEQ,  (VDST) + (4+w)*CH + lane8); }

    // prologue: stage tile 0 into buffer 0
    ATT_STAGE(Ks, Vs, 0)
    __syncthreads();

    int cur = 0;
    #pragma unroll 1
    for (int j0 = 0; j0 < SEQ; j0 += 64) {
        // stage NEXT tile into the other buffer (in flight during compute)
        ATT_STAGE(Ks + (cur^1)*TIL, Vs + (cur^1)*TIL, j0 + 64)

        const short* Kb = Ks + cur*TIL;
        const short* Vb = Vs + cur*TIL;

        // QK^T (swapped): K as A-frag from LDS, Q from regs
        bf16x8 kf[8];
        #pragma unroll
        for (int i = 0; i < 8; i++) kf[i] = *(const bf16x8*)&Kb[koff[i]];
        f32x16 s0 = {}, s1 = {};
        __builtin_amdgcn_s_setprio(1);
        #pragma unroll
        for (int d0 = 0; d0 < 4; d0++) s0 = MFMA32(kf[d0],   qf[d0], s0);
        #pragma unroll
        for (int d0 = 0; d0 < 4; d0++) s1 = MFMA32(kf[4+d0], qf[d0], s1);
        __builtin_amdgcn_s_setprio(0);

        // exp2 (no max subtraction) + row-sum
        #pragma unroll
        for (int r = 0; r < 16; r++) s0[r] = fexp2(s0[r]);
        #pragma unroll
        for (int r = 0; r < 16; r++) s1[r] = fexp2(s1[r]);
        float ts[16];
        #pragma unroll
        for (int r = 0; r < 16; r++) ts[r] = s0[r] + s1[r];
        #pragma unroll
        for (int dd = 8; dd >= 1; dd >>= 1)
            #pragma unroll
            for (int r = 0; r < dd; r++) ts[r] += ts[r + dd];
        lrow += ts[0] + __shfl_xor(ts[0], 32);

        // V frags from LDS (after kf dead -> low register pressure)
        bf16x8 vf[8];
        #pragma unroll
        for (int i = 0; i < 8; i++) vf[i] = *(const bf16x8*)&Vb[voff[i]];

        // T12: cvt_pk + permlane32_swap -> PV
        #pragma unroll
        for (int ks = 0; ks < 4; ks++) {
            const int g = (ks & 1) * 8;
            float e0,e1,e2,e3,e4,e5,e6,e7;
            if (ks < 2) { e0=s0[g+0];e1=s0[g+1];e2=s0[g+2];e3=s0[g+3];
                          e4=s0[g+4];e5=s0[g+5];e6=s0[g+6];e7=s0[g+7]; }
            else        { e0=s1[g+0];e1=s1[g+1];e2=s1[g+2];e3=s1[g+3];
                          e4=s1[g+4];e5=s1[g+5];e6=s1[g+6];e7=s1[g+7]; }
            unsigned u0,u1,u2,u3;
            asm("v_cvt_pk_bf16_f32 %0, %1, %2" : "=v"(u0) : "v"(e0), "v"(e1));
            asm("v_cvt_pk_bf16_f32 %0, %1, %2" : "=v"(u1) : "v"(e2), "v"(e3));
            asm("v_cvt_pk_bf16_f32 %0, %1, %2" : "=v"(u2) : "v"(e4), "v"(e5));
            asm("v_cvt_pk_bf16_f32 %0, %1, %2" : "=v"(u3) : "v"(e6), "v"(e7));
            auto rA = __builtin_amdgcn_permlane32_swap(u0, u2, false, false);
            auto rB = __builtin_amdgcn_permlane32_swap(u1, u3, false, false);
            union { unsigned u[4]; bf16x8 v; } pa;
            pa.u[0] = rA[0]; pa.u[1] = rB[0]; pa.u[2] = rA[1]; pa.u[3] = rB[1];
            __builtin_amdgcn_s_setprio(1);
            o0 = MFMA32(pa.v, vf[ks*2+0], o0);
            o1 = MFMA32(pa.v, vf[ks*2+1], o1);
            __builtin_amdgcn_s_setprio(0);
        }

        __syncthreads();   // next buffer staged (vmcnt drained) + all reads done
        cur ^= 1;
    }

    // epilogue: broadcast 1/l to O rows, write ctx [B,S,1024] bf16
    const float li = 1.f / lrow;
    const int lb = __float_as_int(li);
    #pragma unroll
    for (int r = 0; r < 16; r++) {
        const int crow = (r&3) + 8*(r>>2) + 4*hi;
        const float lv = __int_as_float(__builtin_amdgcn_ds_bpermute(crow*4, lb));
        const size_t base = ((size_t)b*SEQ + q0 + crow)*D_MODEL + h*DKK + l31;
        ctx[base]      = f2b(o0[r] * lv);
        ctx[base + 32] = f2b(o1[r] * lv);
    }
#undef ATT_STAGE
}

// ---------------------------------------------------------------------------
// Row LayerNorm (fp32 in/out)
// ---------------------------------------------------------------------------
__global__ __launch_bounds__(256)
void ln_kernel(const float* __restrict__ hbuf, const float* __restrict__ gamma,
               const float* __restrict__ beta, float* __restrict__ out)
{
    const int row = blockIdx.x;
    const int t = threadIdx.x;
    const float* hp = hbuf + (size_t)row * D_MODEL;
    float4 v = ((const float4*)hp)[t];
    float sum = v.x + v.y + v.z + v.w;
    float sq  = v.x*v.x + v.y*v.y + v.z*v.z + v.w*v.w;
    #pragma unroll
    for (int o = 1; o <= 32; o <<= 1) {
        sum += __shfl_xor(sum, o);
        sq  += __shfl_xor(sq, o);
    }
    __shared__ float s1[4], s2[4];
    if ((t & 63) == 0) { s1[t >> 6] = sum; s2[t >> 6] = sq; }
    __syncthreads();
    sum = s1[0] + s1[1] + s1[2] + s1[3];
    sq  = s2[0] + s2[1] + s2[2] + s2[3];
    const float mean = sum * (1.0f / D_MODEL);
    const float var  = sq * (1.0f / D_MODEL) - mean * mean;
    const float inv  = rsqrtf(var + 1e-5f);
    float4 g  = ((const float4*)gamma)[t];
    float4 be = ((const float4*)beta)[t];
    float4 rr;
    rr.x = (v.x - mean) * inv * g.x + be.x;
    rr.y = (v.y - mean) * inv * g.y + be.y;
    rr.z = (v.z - mean) * inv * g.z + be.z;
    rr.w = (v.w - mean) * inv * g.w + be.w;
    ((float4*)(out + (size_t)row * D_MODEL))[t] = rr;
}

// ---------------------------------------------------------------------------
extern "C" void kernel_launch(void* const* d_in, const int* in_sizes, int n_in,
                              void* d_out, int out_size, void* d_ws, size_t ws_size,
                              hipStream_t stream)
{
    const float* x  = (const float*)d_in[0];
    const float* Wq = (const float*)d_in[1];
    const float* bq = (const float*)d_in[2];
    const float* Wk = (const float*)d_in[3];
    const float* bk = (const float*)d_in[4];
    const float* Wv = (const float*)d_in[5];
    const float* bv = (const float*)d_in[6];
    const float* Wo = (const float*)d_in[7];
    const float* bo = (const float*)d_in[8];
    const float* g  = (const float*)d_in[9];
    const float* be = (const float*)d_in[10];

    short* xb  = (short*)d_ws;
    short* wt3 = xb  + (size_t)4096*1024;
    short* wot = wt3 + (size_t)3072*1024;
    short* qb  = wot + (size_t)1024*1024;
    short* kb  = qb  + (size_t)4096*1024;
    short* vtb = kb  + (size_t)4096*1024;
    short* cxb = vtb + (size_t)4096*1024;
    float* hb  = (float*)(cxb + (size_t)4096*1024);

    prep_weights<<<dim3(32,32,4), 256, 0, stream>>>(Wq, Wk, Wv, Wo, wt3, wot);
    convert_x  <<<2048, 256, 0, stream>>>(x, xb);
    gemm_qkv   <<<256, 512, 0, stream>>>(xb, wt3, bq, bk, bv, qb, kb, vtb);
    attn_mfma  <<<512, 256, 0, stream>>>(qb, kb, vtb, cxb);
    gemm_out   <<<512, 256, 0, stream>>>(cxb, wot, bo, x, hb);
    ln_kernel  <<<MROWS, 256, 0, stream>>>(hb, g, be, (float*)d_out);
}

// Round 12
// 122.613 us; speedup vs baseline: 1.0880x; 1.0167x over previous
//
#include <hip/hip_runtime.h>
#include <math.h>

#define D_MODEL 1024
#define NHEAD   16
#define DKK     64
#define BATCH   2
#define SEQ     2048
#define MROWS   (BATCH*SEQ)   // 4096

typedef __attribute__((ext_vector_type(8)))  short bf16x8;   // 8 bf16 (4 VGPRs)
typedef __attribute__((ext_vector_type(4)))  short bf16x4;   // 8 B
typedef __attribute__((ext_vector_type(4)))  float f32x4;    // 16x16 accumulator
typedef __attribute__((ext_vector_type(16))) float f32x16;   // 32x32 accumulator

#define MFMA(a,b,c)   __builtin_amdgcn_mfma_f32_16x16x32_bf16((a),(b),(c),0,0,0)
#define MFMA32(a,b,c) __builtin_amdgcn_mfma_f32_32x32x16_bf16((a),(b),(c),0,0,0)

#define QSCALE 0.18033688f   // 0.125 * log2(e): folded into Q so p = exp2(S)

#define SBAR() { __builtin_amdgcn_sched_barrier(0); \
                 __builtin_amdgcn_s_barrier();      \
                 __builtin_amdgcn_sched_barrier(0); }

// padded LDS chunk geometry for attn tiles: 8 rows x 64 shorts + 8 pad
#define CH  520              // shorts per 8-row chunk
#define TIL (8*CH)           // 4160 shorts per 64x64 subtile

__device__ __forceinline__ short f2b(float f) {
    unsigned u = __float_as_uint(f);
    unsigned r = (u + 0x7FFFu + ((u >> 16) & 1u)) >> 16;   // RNE
    return (short)r;
}

__device__ __forceinline__ float fexp2(float x) {
    float r; asm("v_exp_f32 %0, %1" : "=v"(r) : "v"(x)); return r;
}

__device__ __forceinline__ void gld_lds16(const void* g, void* l) {
    __builtin_amdgcn_global_load_lds(
        (const __attribute__((address_space(1))) void*)g,
        (__attribute__((address_space(3))) void*)l, 16, 0, 0);
}

// ---------------------------------------------------------------------------
// Weight prep: W[1024][1024] f32 -> WT bf16 [N][K].  z=0..2 -> wt3, z=3 -> wot
// ---------------------------------------------------------------------------
__global__ __launch_bounds__(256)
void prep_weights(const float* __restrict__ Wq, const float* __restrict__ Wk,
                  const float* __restrict__ Wv, const float* __restrict__ Wo,
                  short* __restrict__ wt3, short* __restrict__ wot)
{
    const int z = blockIdx.z;
    const float* W = z==0 ? Wq : z==1 ? Wk : z==2 ? Wv : Wo;
    short* dst = (z < 3) ? (wt3 + (size_t)z*1024*1024) : wot;
    __shared__ float tile[32][33];
    const int tx = threadIdx.x & 31, ty = threadIdx.x >> 5;
    const int c0 = blockIdx.x*32, r0 = blockIdx.y*32;
    #pragma unroll
    for (int i = 0; i < 4; i++)
        tile[ty + i*8][tx] = W[(size_t)(r0 + ty + i*8)*1024 + c0 + tx];
    __syncthreads();
    #pragma unroll
    for (int i = 0; i < 4; i++)
        dst[(size_t)(c0 + ty + i*8)*1024 + r0 + tx] = f2b(tile[tx][ty + i*8]);
}

__global__ __launch_bounds__(256)
void convert_x(const float* __restrict__ x, short* __restrict__ xb)
{
    const int i = (blockIdx.x*256 + threadIdx.x) * 8;
    float4 a = *(const float4*)(x + i);
    float4 c = *(const float4*)(x + i + 4);
    bf16x8 v;
    v[0]=f2b(a.x); v[1]=f2b(a.y); v[2]=f2b(a.z); v[3]=f2b(a.w);
    v[4]=f2b(c.x); v[5]=f2b(c.y); v[6]=f2b(c.z); v[7]=f2b(c.w);
    *(bf16x8*)(xb + i) = v;
}

// ---------------------------------------------------------------------------
// Fused QKV GEMM, 256x192-tile 8-phase schedule (T2+T3+T4+T5).  (round-9 form)
// ---------------------------------------------------------------------------
__global__ __launch_bounds__(512, 2)
void gemm_qkv(const short* __restrict__ A, const short* __restrict__ Bt,
              const float* __restrict__ bq, const float* __restrict__ bk,
              const float* __restrict__ bv,
              short* __restrict__ qb, short* __restrict__ kb, short* __restrict__ vtb)
{
    __shared__ short Ab[2*16384];   // [buf][256 rows][64 k]   64 KB
    __shared__ short Bb[2*12288];   // [buf][192 rows][64 k]   48 KB

    const int t = threadIdx.x;              // 0..511
    const int w = t >> 6, lane = t & 63;
    const int r = lane & 15, g4 = lane >> 4;
    const int wm = w >> 2, wn = w & 3;      // wave grid 2(M) x 4(N)

    // XCD rect swizzle: 256 blocks = 8 XCD x 32; each XCD a 4m x 8n rect.
    const int bid = blockIdx.x;
    const int xcd = bid & 7, idx = bid >> 3;          // idx 0..31
    const int mi  = (xcd >> 1) * 4 + (idx & 3);       // 0..15
    const int ni  = (xcd & 1) * 8 + (idx >> 2);       // 0..15
    const int m0 = mi * 256, n0 = ni * 192;

    const int srow = t >> 3;                          // 0..63
    const int scol = ((t & 7) ^ (srow & 7)) * 8;

    f32x4 acc[8][3] = {};
    bf16x8 bfr[2][3];   // B-frags per k-slice, live across the two m-halves

#define QKV_STAGE(P, KT)                                                      \
    { const int kk = (KT) * 64 + scol;                                        \
      _Pragma("unroll")                                                       \
      for (int a = 0; a < 4; a++)                                             \
          gld_lds16(A + (size_t)(m0 + a*64 + srow)*1024 + kk,                 \
                    Ab + (P)*16384 + a*4096 + t*8);                           \
      _Pragma("unroll")                                                       \
      for (int p2 = 0; p2 < 3; p2++)                                          \
          gld_lds16(Bt + (size_t)(n0 + p2*64 + srow)*1024 + kk,               \
                    Bb + (P)*12288 + p2*4096 + t*8); }

#define QKV_PHASE(P, MH, KS, LOADB)                                           \
    { const short* Abase = Ab + (P)*16384 + wm*8192;                          \
      bf16x8 af[4];                                                           \
      _Pragma("unroll")                                                       \
      for (int i = 0; i < 4; i++)                                             \
          af[i] = *(const bf16x8*)&Abase[((MH)*64 + i*16 + r)*64 +            \
                                         (((KS)*4 + g4) ^ (r&7))*8];          \
      if (LOADB) {                                                            \
          const short* Bbase = Bb + (P)*12288;                                \
          _Pragma("unroll")                                                   \
          for (int j = 0; j < 3; j++)                                         \
              bfr[KS][j] = *(const bf16x8*)&Bbase[(wn*48 + j*16 + r)*64 +     \
                                                  (((KS)*4 + g4) ^ (r&7))*8]; \
      }                                                                       \
      SBAR();                                                                 \
      __builtin_amdgcn_s_setprio(1);                                          \
      _Pragma("unroll")                                                       \
      for (int i = 0; i < 4; i++)                                             \
          _Pragma("unroll")                                                   \
          for (int j = 0; j < 3; j++)                                         \
              acc[(MH)*4+i][j] = MFMA(af[i], bfr[KS][j], acc[(MH)*4+i][j]);   \
      __builtin_amdgcn_s_setprio(0);                                          \
      SBAR(); }

    QKV_STAGE(0, 0)
    QKV_STAGE(1, 1)
    asm volatile("s_waitcnt vmcnt(7)" ::: "memory");
    __builtin_amdgcn_s_barrier();
    __builtin_amdgcn_sched_barrier(0);

    int p = 0;
    #pragma unroll 1
    for (int kt = 0; kt < 16; kt++) {
        QKV_PHASE(p, 0, 0, 1)
        QKV_PHASE(p, 1, 0, 0)
        QKV_PHASE(p, 0, 1, 1)
        QKV_PHASE(p, 1, 1, 0)
        if (kt < 14) {
            QKV_STAGE(p, kt + 2)
            asm volatile("s_waitcnt vmcnt(7)" ::: "memory");  // kt+1 landed
        } else {
            asm volatile("s_waitcnt vmcnt(0)" ::: "memory");  // tail drain
        }
        __builtin_amdgcn_s_barrier();
        __builtin_amdgcn_sched_barrier(0);
        p ^= 1;
    }
#undef QKV_STAGE
#undef QKV_PHASE

    #pragma unroll
    for (int n = 0; n < 3; n++) {
        const int colbase = n0 + wn*48 + n*16;
        const int proj    = colbase >> 10;
        const int within  = colbase & 1023;
        const int h       = within >> 6;
        const int d       = (within & 63) + r;
        const float* bias = (proj == 0) ? bq : (proj == 1) ? bk : bv;
        const float bval  = bias[within + r];
        #pragma unroll
        for (int m = 0; m < 8; m++) {
            const int growb = m0 + wm*128 + m*16 + g4*4;
            const int bidx  = growb >> 11;
            const int s     = growb & 2047;
            if (proj == 0) {
                #pragma unroll
                for (int i = 0; i < 4; i++)
                    qb[((size_t)(bidx*NHEAD + h)*SEQ + s + i)*DKK + d] =
                        f2b((acc[m][n][i] + bval) * QSCALE);
            } else if (proj == 1) {
                #pragma unroll
                for (int i = 0; i < 4; i++)
                    kb[((size_t)(bidx*NHEAD + h)*SEQ + s + i)*DKK + d] =
                        f2b(acc[m][n][i] + bval);
            } else {
                bf16x4 pk;
                #pragma unroll
                for (int i = 0; i < 4; i++) pk[i] = f2b(acc[m][n][i] + bval);
                *(bf16x4*)(vtb + ((size_t)(bidx*NHEAD + h)*DKK + d)*SEQ + s) = pk;
            }
        }
    }
}

// ---------------------------------------------------------------------------
// Wo GEMM + bias + residual -> h fp32.  128x64 tile, double-buffered + swizzle.
// ---------------------------------------------------------------------------
__global__ __launch_bounds__(256)
void gemm_out(const short* __restrict__ A, const short* __restrict__ Bt,
              const float* __restrict__ bo, const float* __restrict__ resid,
              float* __restrict__ hb)
{
    __shared__ short As[2*128*32];   // 16 KB
    __shared__ short Bs[2*64*32];    // 8 KB
    const int t = threadIdx.x;
    const int w = t >> 6, lane = t & 63;
    const int r = lane & 15, g4 = lane >> 4;
    const int wr = w >> 1, wc = w & 1;

    const int bid = blockIdx.x;
    const int xcd = bid & 7, idx = bid >> 3;          // idx 0..63
    const int mi  = (xcd >> 1) * 8 + (idx & 7);       // 0..31
    const int ni  = (xcd & 1) * 8 + (idx >> 3);       // 0..15
    const int m0 = mi * 128, n0 = ni * 64;

    const int srow = lane >> 2, su = lane & 3;

    f32x4 acc[4][2] = {};

#define OUT_STAGE(BUF, K0)                                                     \
    { const int kk = (K0) & 1023;                                              \
      _Pragma("unroll")                                                        \
      for (int c = 0; c < 2; c++) {                                            \
          const int row = w*32 + c*16 + srow;                                  \
          gld_lds16(A + (size_t)(m0+row)*1024 + kk + 8*(su ^ ((row>>1)&3)),    \
                    As + (BUF)*4096 + w*1024 + c*512);                         \
      }                                                                        \
      { const int row = w*16 + srow;                                           \
        gld_lds16(Bt + (size_t)(n0+row)*1024 + kk + 8*(su ^ ((row>>1)&3)),     \
                  Bs + (BUF)*2048 + w*512); } }

    OUT_STAGE(0, 0)
    __syncthreads();

    int cur = 0;
    #pragma unroll 1
    for (int k0 = 0; k0 < 1024; k0 += 32) {
        OUT_STAGE(cur^1, k0 + 32)
        const short* Abase = As + cur*4096;
        const short* Bbase = Bs + cur*2048;
        bf16x8 af[4], bfr[2];
        #pragma unroll
        for (int m = 0; m < 4; m++) {
            const int row = wr*64 + m*16 + r;
            af[m] = *(const bf16x8*)&Abase[row*32 + (g4 ^ ((row>>1)&3))*8];
        }
        #pragma unroll
        for (int n = 0; n < 2; n++) {
            const int row = wc*32 + n*16 + r;
            bfr[n] = *(const bf16x8*)&Bbase[row*32 + (g4 ^ ((row>>1)&3))*8];
        }
        __builtin_amdgcn_s_setprio(1);
        #pragma unroll
        for (int m = 0; m < 4; m++)
            #pragma unroll
            for (int n = 0; n < 2; n++)
                acc[m][n] = MFMA(af[m], bfr[n], acc[m][n]);
        __builtin_amdgcn_s_setprio(0);
        __syncthreads();
        cur ^= 1;
    }
#undef OUT_STAGE

    #pragma unroll
    for (int n = 0; n < 2; n++) {
        const int col = n0 + wc*32 + n*16 + r;
        const float bval = bo[col];
        #pragma unroll
        for (int m = 0; m < 4; m++) {
            #pragma unroll
            for (int i = 0; i < 4; i++) {
                const int grow = m0 + wr*64 + m*16 + g4*4 + i;
                const size_t ofs = (size_t)grow*1024 + col;
                hb[ofs] = acc[m][n][i] + bval + resid[ofs];
            }
        }
    }
}

// ---------------------------------------------------------------------------
// Swapped-QK 32x32 MFMA flash attention.  Round-12: KVBLK=128 per iteration
// as TWO independent 64-row subtile chains (separate s-states and separate
// O-accumulators, merged once in the epilogue) -> 2x in-wave ILP on the
// QK-chain / exp2 / PV-chain, and ONE barrier per 128 KV rows (halves
// barrier+drain count).  LDS 65 KB/block (2 blocks/CU).  No max tracking;
// Q pre-scaled by QSCALE.
// ---------------------------------------------------------------------------
__global__ __launch_bounds__(256, 2)
void attn_mfma(const short* __restrict__ Q, const short* __restrict__ K,
               const short* __restrict__ VT, short* __restrict__ ctx)
{
    __shared__ short Ks[4*TIL];   // [buf][sub]  ~32.5 KB
    __shared__ short Vs[4*TIL];   // ~32.5 KB

    const int t = threadIdx.x;
    const int w = t >> 6, lane = t & 63;
    const int l31 = lane & 31, hi = lane >> 5;
    const int srow8 = lane >> 3, su = lane & 7;
    const int lane8 = lane * 8;            // element offset within chunk
    const int swz8  = (su ^ srow8) * 8;    // inverse-swizzle on global source

    // T1: XCD-aware swizzle (512 blocks; XCD c owns bh pairs 4c..4c+3).
    const int bid     = blockIdx.x;
    const int logical = (bid & 7) * 64 + (bid >> 3);
    const int bh_lin  = logical >> 4;
    const int qt      = logical & 15;
    const int b = bh_lin >> 4, h = bh_lin & 15;
    const int q0 = qt * 128 + w * 32;

    const size_t bh = (size_t)b * NHEAD + h;
    const short* Qp = Q  + bh * SEQ * DKK;
    const short* Kp = K  + bh * SEQ * DKK;
    const short* Vp = VT + bh * DKK * SEQ;

    // per-thread staging source bases (row = w*8 + srow8, +32 for pass 2)
    const short* kstage = Kp + (size_t)(w*8 + srow8) * DKK + swz8;
    const short* vstage = Vp + (size_t)(w*8 + srow8) * SEQ + swz8;

    // Q B-frags: lane holds Q[q0+l31][d0*16 + hi*8 + j]  (pre-scaled)
    bf16x8 qf[4];
    #pragma unroll
    for (int d0 = 0; d0 < 4; d0++)
        qf[d0] = *(const bf16x8*)(Qp + (size_t)(q0 + l31)*DKK + d0*16 + hi*8);

    // LDS read offsets (subtile-invariant; swizzled slot + padded chunk)
    int koff[8], voff[8];
    #pragma unroll
    for (int i = 0; i < 8; i++) {
        const int kchunk = (i>>2)*4 + (l31>>3);
        koff[i] = kchunk*CH + (l31&7)*64 + ((((i&3)*2 + hi) ^ (l31&7)) * 8);
        const int vchunk = (i&1)*4 + (l31>>3);
        voff[i] = vchunk*CH + (l31&7)*64 + ((((i>>1)*2 + hi) ^ (l31&7)) * 8);
    }

    f32x16 o0A = {}, o1A = {}, o0B = {}, o1B = {};
    float lrow = 0.f;

#define ATT_STAGE(KDST, VDST, J)                                               \
    { const size_t jj = (size_t)((J) & (SEQ-1));                               \
      const short* ksrc = kstage + jj*DKK;                                     \
      gld_lds16(ksrc,           (KDST) + w*CH + lane8);                        \
      gld_lds16(ksrc + 32*DKK,  (KDST) + (4+w)*CH + lane8);                    \
      const short* vsrc = vstage + jj;                                         \
      gld_lds16(vsrc,           (VDST) + w*CH + lane8);                        \
      gld_lds16(vsrc + 32*SEQ,  (VDST) + (4+w)*CH + lane8); }

// QK^T for one 64-row subtile: K as A-frag from LDS, Q from regs.
#define QK_SUB(KB, S0, S1)                                                     \
    { bf16x8 kf[8];                                                            \
      _Pragma("unroll")                                                        \
      for (int i = 0; i < 8; i++) kf[i] = *(const bf16x8*)&(KB)[koff[i]];      \
      _Pragma("unroll")                                                        \
      for (int d0 = 0; d0 < 4; d0++) S0 = MFMA32(kf[d0],   qf[d0], S0);        \
      _Pragma("unroll")                                                        \
      for (int d0 = 0; d0 < 4; d0++) S1 = MFMA32(kf[4+d0], qf[d0], S1); }

// PV for one subtile (T12: cvt_pk + permlane32_swap, P stays in regs).
#define PV_SUB(S0, S1, VB, O0, O1)                                             \
    { bf16x8 vf[8];                                                            \
      _Pragma("unroll")                                                        \
      for (int i = 0; i < 8; i++) vf[i] = *(const bf16x8*)&(VB)[voff[i]];      \
      _Pragma("unroll")                                                        \
      for (int ks = 0; ks < 4; ks++) {                                         \
        const int g = (ks & 1) * 8;                                            \
        float e0,e1,e2,e3,e4,e5,e6,e7;                                         \
        if (ks < 2) { e0=S0[g+0];e1=S0[g+1];e2=S0[g+2];e3=S0[g+3];             \
                      e4=S0[g+4];e5=S0[g+5];e6=S0[g+6];e7=S0[g+7]; }           \
        else        { e0=S1[g+0];e1=S1[g+1];e2=S1[g+2];e3=S1[g+3];             \
                      e4=S1[g+4];e5=S1[g+5];e6=S1[g+6];e7=S1[g+7]; }           \
        unsigned u0,u1,u2,u3;                                                  \
        asm("v_cvt_pk_bf16_f32 %0, %1, %2" : "=v"(u0) : "v"(e0), "v"(e1));     \
        asm("v_cvt_pk_bf16_f32 %0, %1, %2" : "=v"(u1) : "v"(e2), "v"(e3));     \
        asm("v_cvt_pk_bf16_f32 %0, %1, %2" : "=v"(u2) : "v"(e4), "v"(e5));     \
        asm("v_cvt_pk_bf16_f32 %0, %1, %2" : "=v"(u3) : "v"(e6), "v"(e7));     \
        auto rA = __builtin_amdgcn_permlane32_swap(u0, u2, false, false);      \
        auto rB = __builtin_amdgcn_permlane32_swap(u1, u3, false, false);      \
        union { unsigned u[4]; bf16x8 v; } pa;                                 \
        pa.u[0] = rA[0]; pa.u[1] = rB[0]; pa.u[2] = rA[1]; pa.u[3] = rB[1];    \
        O0 = MFMA32(pa.v, vf[ks*2+0], O0);                                     \
        O1 = MFMA32(pa.v, vf[ks*2+1], O1);                                     \
      } }

    // prologue: stage KV pair 0 (subtiles 0,64) into buffer 0
    ATT_STAGE(Ks,       Vs,       0)
    ATT_STAGE(Ks + TIL, Vs + TIL, 64)
    __syncthreads();

    int cur = 0;
    #pragma unroll 1
    for (int j0 = 0; j0 < SEQ; j0 += 128) {
        // stage NEXT pair into the other buffer (in flight during compute)
        {
            const int nb = (cur^1)*2*TIL;
            ATT_STAGE(Ks + nb,       Vs + nb,       j0 + 128)
            ATT_STAGE(Ks + nb + TIL, Vs + nb + TIL, j0 + 192)
        }

        const short* KbA = Ks + cur*2*TIL;
        const short* VbA = Vs + cur*2*TIL;
        const short* KbB = KbA + TIL;
        const short* VbB = VbA + TIL;

        // two independent QK chains
        f32x16 s0A = {}, s1A = {}, s0B = {}, s1B = {};
        QK_SUB(KbA, s0A, s1A)
        QK_SUB(KbB, s0B, s1B)

        // exp2 (no max subtraction), all 64 values, independent
        #pragma unroll
        for (int r = 0; r < 16; r++) s0A[r] = fexp2(s0A[r]);
        #pragma unroll
        for (int r = 0; r < 16; r++) s1A[r] = fexp2(s1A[r]);
        #pragma unroll
        for (int r = 0; r < 16; r++) s0B[r] = fexp2(s0B[r]);
        #pragma unroll
        for (int r = 0; r < 16; r++) s1B[r] = fexp2(s1B[r]);

        // one tree-sum for the whole 128-KV pair
        float ts[16];
        #pragma unroll
        for (int r = 0; r < 16; r++) ts[r] = (s0A[r] + s1A[r]) + (s0B[r] + s1B[r]);
        #pragma unroll
        for (int dd = 8; dd >= 1; dd >>= 1)
            #pragma unroll
            for (int r = 0; r < dd; r++) ts[r] += ts[r + dd];
        lrow += ts[0] + __shfl_xor(ts[0], 32);

        // two independent PV chains into separate accumulators
        PV_SUB(s0A, s1A, VbA, o0A, o1A)
        PV_SUB(s0B, s1B, VbB, o0B, o1B)

        __syncthreads();   // next pair staged (vmcnt drained) + all reads done
        cur ^= 1;
    }

    // epilogue: merge subtile accumulators, broadcast 1/l, write ctx bf16
    const float li = 1.f / lrow;
    const int lb = __float_as_int(li);
    #pragma unroll
    for (int r = 0; r < 16; r++) {
        const int crow = (r&3) + 8*(r>>2) + 4*hi;
        const float lv = __int_as_float(__builtin_amdgcn_ds_bpermute(crow*4, lb));
        const size_t base = ((size_t)b*SEQ + q0 + crow)*D_MODEL + h*DKK + l31;
        ctx[base]      = f2b((o0A[r] + o0B[r]) * lv);
        ctx[base + 32] = f2b((o1A[r] + o1B[r]) * lv);
    }
#undef ATT_STAGE
#undef QK_SUB
#undef PV_SUB
}

// ---------------------------------------------------------------------------
// Row LayerNorm (fp32 in/out)
// ---------------------------------------------------------------------------
__global__ __launch_bounds__(256)
void ln_kernel(const float* __restrict__ hbuf, const float* __restrict__ gamma,
               const float* __restrict__ beta, float* __restrict__ out)
{
    const int row = blockIdx.x;
    const int t = threadIdx.x;
    const float* hp = hbuf + (size_t)row * D_MODEL;
    float4 v = ((const float4*)hp)[t];
    float sum = v.x + v.y + v.z + v.w;
    float sq  = v.x*v.x + v.y*v.y + v.z*v.z + v.w*v.w;
    #pragma unroll
    for (int o = 1; o <= 32; o <<= 1) {
        sum += __shfl_xor(sum, o);
        sq  += __shfl_xor(sq, o);
    }
    __shared__ float s1[4], s2[4];
    if ((t & 63) == 0) { s1[t >> 6] = sum; s2[t >> 6] = sq; }
    __syncthreads();
    sum = s1[0] + s1[1] + s1[2] + s1[3];
    sq  = s2[0] + s2[1] + s2[2] + s2[3];
    const float mean = sum * (1.0f / D_MODEL);
    const float var  = sq * (1.0f / D_MODEL) - mean * mean;
    const float inv  = rsqrtf(var + 1e-5f);
    float4 g  = ((const float4*)gamma)[t];
    float4 be = ((const float4*)beta)[t];
    float4 rr;
    rr.x = (v.x - mean) * inv * g.x + be.x;
    rr.y = (v.y - mean) * inv * g.y + be.y;
    rr.z = (v.z - mean) * inv * g.z + be.z;
    rr.w = (v.w - mean) * inv * g.w + be.w;
    ((float4*)(out + (size_t)row * D_MODEL))[t] = rr;
}

// ---------------------------------------------------------------------------
extern "C" void kernel_launch(void* const* d_in, const int* in_sizes, int n_in,
                              void* d_out, int out_size, void* d_ws, size_t ws_size,
                              hipStream_t stream)
{
    const float* x  = (const float*)d_in[0];
    const float* Wq = (const float*)d_in[1];
    const float* bq = (const float*)d_in[2];
    const float* Wk = (const float*)d_in[3];
    const float* bk = (const float*)d_in[4];
    const float* Wv = (const float*)d_in[5];
    const float* bv = (const float*)d_in[6];
    const float* Wo = (const float*)d_in[7];
    const float* bo = (const float*)d_in[8];
    const float* g  = (const float*)d_in[9];
    const float* be = (const float*)d_in[10];

    short* xb  = (short*)d_ws;
    short* wt3 = xb  + (size_t)4096*1024;
    short* wot = wt3 + (size_t)3072*1024;
    short* qb  = wot + (size_t)1024*1024;
    short* kb  = qb  + (size_t)4096*1024;
    short* vtb = kb  + (size_t)4096*1024;
    short* cxb = vtb + (size_t)4096*1024;
    float* hb  = (float*)(cxb + (size_t)4096*1024);

    prep_weights<<<dim3(32,32,4), 256, 0, stream>>>(Wq, Wk, Wv, Wo, wt3, wot);
    convert_x  <<<2048, 256, 0, stream>>>(x, xb);
    gemm_qkv   <<<256, 512, 0, stream>>>(xb, wt3, bq, bk, bv, qb, kb, vtb);
    attn_mfma  <<<512, 256, 0, stream>>>(qb, kb, vtb, cxb);
    gemm_out   <<<512, 256, 0, stream>>>(cxb, wot, bo, x, hb);
    ln_kernel  <<<MROWS, 256, 0, stream>>>(hb, g, be, (float*)d_out);
}